// Round 5
// baseline (3067.259 us; speedup 1.0000x reference)
//
#include <hip/hip_runtime.h>

#define NN 100000
#define NE 3200000
#define NR 32
#define DIM 64
#define RB 512                          // rows per bucket (2^9)
#define NB ((NN + RB - 1) / RB)         // 196 buckets
#define EPB 8192                        // edges per block in bucket kernels
#define NBLK_E ((NE + EPB - 1) / EPB)   // 391

typedef unsigned int u32;
typedef unsigned long long u64;

// ---------------------------------------------------------------------------
// ws layout (38.4 MB):
//   int cntA[NB], cntR[NB], curA[NB], curR[NB], baseA[NB], baseR[NB]  (<8KB)
//   u64 recsA[NE] @ +8192   main edges, bucketed: {hi: val f32, lo: rowlow<<17 | col}
//   u32 recsR[NE]           rel  edges, bucketed: {val bf16 << 16 | rowlow<<5 | rel}
// ---------------------------------------------------------------------------

// K1a: per-bucket edge counts (LDS-aggregated -> 2*NB global atomics per block)
__global__ __launch_bounds__(256) void count_kernel(
    const int* __restrict__ row, const int* __restrict__ row_r,
    int* __restrict__ cntA, int* __restrict__ cntR)
{
    __shared__ int lh[2 * NB];
    for (int i = threadIdx.x; i < 2 * NB; i += 256) lh[i] = 0;
    __syncthreads();
    int base = blockIdx.x * EPB;
    for (int i = 0; i < EPB / 256; ++i) {
        int e = base + i * 256 + threadIdx.x;
        if (e < NE) {
            atomicAdd(&lh[row[e] >> 9], 1);
            atomicAdd(&lh[NB + (row_r[e] >> 9)], 1);
        }
    }
    __syncthreads();
    for (int t = threadIdx.x; t < NB; t += 256) {
        if (lh[t])      atomicAdd(&cntA[t], lh[t]);
        if (lh[NB + t]) atomicAdd(&cntR[t], lh[NB + t]);
    }
}

// K2: exclusive scan of both count arrays (NB<=256), init cursors
__global__ __launch_bounds__(256) void scan_kernel(
    const int* __restrict__ cntA, const int* __restrict__ cntR,
    int* __restrict__ baseA, int* __restrict__ baseR,
    int* __restrict__ curA, int* __restrict__ curR)
{
    __shared__ int s[256];
    int t = threadIdx.x;
    int v = (t < NB) ? cntA[t] : 0;
    s[t] = v; __syncthreads();
    for (int o = 1; o < 256; o <<= 1) {
        int x = (t >= o) ? s[t - o] : 0; __syncthreads();
        s[t] += x; __syncthreads();
    }
    if (t < NB) { baseA[t] = s[t] - v; curA[t] = s[t] - v; }
    __syncthreads();
    int v2 = (t < NB) ? cntR[t] : 0;
    s[t] = v2; __syncthreads();
    for (int o = 1; o < 256; o <<= 1) {
        int x = (t >= o) ? s[t - o] : 0; __syncthreads();
        s[t] += x; __syncthreads();
    }
    if (t < NB) { baseR[t] = s[t] - v2; curR[t] = s[t] - v2; }
}

// K1b: scatter edges into bucket regions (block-ranked, coalesced runs)
__global__ __launch_bounds__(256) void bucket_kernel(
    const int* __restrict__ row, const int* __restrict__ col,
    const float* __restrict__ vals,
    const int* __restrict__ row_r, const int* __restrict__ rel_i,
    const float* __restrict__ vals_r,
    int* __restrict__ curA, int* __restrict__ curR,
    u64* __restrict__ recsA, u32* __restrict__ recsR)
{
    __shared__ int lhA[NB], lhR[NB], lbA[NB], lbR[NB];
    for (int i = threadIdx.x; i < NB; i += 256) { lhA[i] = 0; lhR[i] = 0; }
    __syncthreads();
    int base = blockIdx.x * EPB;
    for (int i = 0; i < EPB / 256; ++i) {
        int e = base + i * 256 + threadIdx.x;
        if (e < NE) {
            atomicAdd(&lhA[row[e] >> 9], 1);
            atomicAdd(&lhR[row_r[e] >> 9], 1);
        }
    }
    __syncthreads();
    for (int t = threadIdx.x; t < NB; t += 256) {
        lbA[t] = lhA[t] ? atomicAdd(&curA[t], lhA[t]) : 0;
        lbR[t] = lhR[t] ? atomicAdd(&curR[t], lhR[t]) : 0;
    }
    __syncthreads();
    for (int i = threadIdx.x; i < NB; i += 256) { lhA[i] = 0; lhR[i] = 0; }
    __syncthreads();
    for (int i = 0; i < EPB / 256; ++i) {
        int e = base + i * 256 + threadIdx.x;
        if (e < NE) {
            int r = row[e], bk = r >> 9;
            int rank = atomicAdd(&lhA[bk], 1);
            union { float f; u32 u; } uv; uv.f = vals[e];
            u32 lo = (u32)col[e] | ((u32)(r & (RB - 1)) << 17);
            recsA[lbA[bk] + rank] = ((u64)uv.u << 32) | lo;

            int r2 = row_r[e], bk2 = r2 >> 9;
            int rank2 = atomicAdd(&lhR[bk2], 1);
            union { float f; u32 u; } uw; uw.f = vals_r[e];
            u32 vb = (uw.u + 0x8000u) & 0xFFFF0000u;   // bf16 round-to-nearest
            recsR[lbR[bk2] + rank2] = vb | ((u32)(r2 & (RB - 1)) << 5) | (u32)rel_i[e];
        }
    }
}

// K3: per-bucket LDS accumulation + fused epilogue
__global__ __launch_bounds__(512) void agg_kernel(
    const float* __restrict__ ego, const float* __restrict__ rel_emb,
    const int* __restrict__ cntA, const int* __restrict__ baseA,
    const int* __restrict__ cntR, const int* __restrict__ baseR,
    const u64* __restrict__ recsA, const u32* __restrict__ recsR,
    const float* __restrict__ W1, const float* __restrict__ b1,
    const float* __restrict__ W2, const float* __restrict__ b2,
    float* __restrict__ out)
{
    extern __shared__ float smem[];
    float* tile  = smem;                  // RB*DIM floats (128 KB)
    float* srel  = tile + RB * DIM;       // NR*DIM floats (8 KB), pre-scaled 0.1x
    float* pairb = srel + NR * DIM;       // 8 waves * 128 floats (4 KB)

    const int tid  = threadIdx.x;
    const int wave = tid >> 6;
    const int lane = tid & 63;
    const int b    = blockIdx.x;

    for (int i = tid; i < RB * DIM; i += 512) tile[i] = 0.0f;
    for (int i = tid; i < NR * DIM; i += 512) srel[i] = 0.1f * rel_emb[i];
    __syncthreads();

    // ---- rel edges: tile[rowlow][:] += val * 0.1*rel_emb[rel][:] ----
    {
        int s0 = baseR[b], cnt = cntR[b];
        for (int chunk = wave * 64; chunk < cnt; chunk += 8 * 64) {
            int m = min(64, cnt - chunk);
            u32 rec = 0;
            if (lane < m) rec = recsR[s0 + chunk + lane];
            if (m == 64) {
                #pragma unroll 64
                for (int j = 0; j < 64; ++j) {
                    u32 lj = (u32)__builtin_amdgcn_readlane((int)rec, j);
                    float v = __uint_as_float(lj & 0xFFFF0000u);
                    int rl = (int)((lj >> 5) & (RB - 1));
                    atomicAdd(&tile[rl * DIM + lane], v * srel[(lj & 31) * DIM + lane]);
                }
            } else {
                for (int j = 0; j < m; ++j) {
                    u32 lj = (u32)__builtin_amdgcn_readlane((int)rec, j);
                    float v = __uint_as_float(lj & 0xFFFF0000u);
                    int rl = (int)((lj >> 5) & (RB - 1));
                    atomicAdd(&tile[rl * DIM + lane], v * srel[(lj & 31) * DIM + lane]);
                }
            }
        }
    }
    // ---- main edges: tile[rowlow][:] += val * ego[col][:] ----
    {
        int s0 = baseA[b], cnt = cntA[b];
        for (int chunk = wave * 64; chunk < cnt; chunk += 8 * 64) {
            int m = min(64, cnt - chunk);
            u64 rec = 0;
            if (lane < m) rec = recsA[s0 + chunk + lane];
            u32 lo = (u32)rec, hi = (u32)(rec >> 32);
            if (m == 64) {
                #pragma unroll 64
                for (int j = 0; j < 64; ++j) {
                    u32 lj = (u32)__builtin_amdgcn_readlane((int)lo, j);
                    float v = __uint_as_float((u32)__builtin_amdgcn_readlane((int)hi, j));
                    int c  = (int)(lj & 0x1FFFFu);
                    int rl = (int)(lj >> 17);
                    atomicAdd(&tile[rl * DIM + lane], v * ego[(size_t)c * DIM + lane]);
                }
            } else {
                for (int j = 0; j < m; ++j) {
                    u32 lj = (u32)__builtin_amdgcn_readlane((int)lo, j);
                    float v = __uint_as_float((u32)__builtin_amdgcn_readlane((int)hi, j));
                    int c  = (int)(lj & 0x1FFFFu);
                    int rl = (int)(lj >> 17);
                    atomicAdd(&tile[rl * DIM + lane], v * ego[(size_t)c * DIM + lane]);
                }
            }
        }
    }
    __syncthreads();

    // ---- epilogue: W in registers, addv/biv exchanged through wave-local LDS ----
    float w1s[64], w2s[64];
    {
        const float4* W1v = (const float4*)(W1 + (size_t)lane * DIM);
        const float4* W2v = (const float4*)(W2 + (size_t)lane * DIM);
        #pragma unroll 16
        for (int i = 0; i < 16; ++i) {
            float4 a = W1v[i];
            w1s[4*i+0] = a.x; w1s[4*i+1] = a.y; w1s[4*i+2] = a.z; w1s[4*i+3] = a.w;
            float4 c = W2v[i];
            w2s[4*i+0] = c.x; w2s[4*i+1] = c.y; w2s[4*i+2] = c.z; w2s[4*i+3] = c.w;
        }
    }
    float bb1 = b1[lane], bb2 = b2[lane];
    float* pb = pairb + wave * 128;

    for (int t = 0; t < 64; ++t) {
        int nl = wave * 64 + t;
        int n  = b * RB + nl;
        if (n >= NN) break;                         // uniform per wave
        float sd = tile[nl * DIM + lane];
        float eg = ego[(size_t)n * DIM + lane];
        float av = eg + sd;                         // ego + side
        float bv = eg * sd;                         // ego * side
        ((float2*)pb)[lane] = make_float2(av, bv);  // wave-local exchange (in-order DS)
        float acc1 = bb1, acc2 = bb2;
        #pragma unroll 64
        for (int k = 0; k < 64; ++k) {
            float2 ab = ((float2*)pb)[k];           // uniform addr -> broadcast read
            acc1 += ab.x * w1s[k];
            acc2 += ab.y * w2s[k];
        }
        acc1 = acc1 > 0.0f ? acc1 : 0.01f * acc1;
        acc2 = acc2 > 0.0f ? acc2 : 0.01f * acc2;
        out[(size_t)n * DIM + lane] = acc1 + acc2;
    }
}

extern "C" void kernel_launch(void* const* d_in, const int* in_sizes, int n_in,
                              void* d_out, int out_size, void* d_ws, size_t ws_size,
                              hipStream_t stream)
{
    const float* ego    = (const float*)d_in[0];
    const float* rel    = (const float*)d_in[1];
    const int*   row    = (const int*)  d_in[2];
    const int*   col    = (const int*)  d_in[3];
    const float* vals   = (const float*)d_in[4];
    const int*   row_r  = (const int*)  d_in[5];
    const int*   rel_i  = (const int*)  d_in[6];
    const float* vals_r = (const float*)d_in[7];
    const float* W1     = (const float*)d_in[8];
    const float* b1     = (const float*)d_in[9];
    const float* W2     = (const float*)d_in[10];
    const float* b2     = (const float*)d_in[11];
    float* out = (float*)d_out;

    int* cntA  = (int*)d_ws;
    int* cntR  = cntA + NB;
    int* curA  = cntR + NB;
    int* curR  = curA + NB;
    int* baseA = curR + NB;
    int* baseR = baseA + NB;
    u64* recsA = (u64*)((char*)d_ws + 8192);
    u32* recsR = (u32*)(recsA + NE);

    hipMemsetAsync(d_ws, 0, 8192, stream);        // zero counters

    count_kernel<<<NBLK_E, 256, 0, stream>>>(row, row_r, cntA, cntR);
    scan_kernel<<<1, 256, 0, stream>>>(cntA, cntR, baseA, baseR, curA, curR);
    bucket_kernel<<<NBLK_E, 256, 0, stream>>>(row, col, vals, row_r, rel_i, vals_r,
                                              curA, curR, recsA, recsR);

    const int smem_bytes = (RB * DIM + NR * DIM + 8 * 128) * sizeof(float); // 143360
    hipFuncSetAttribute((const void*)agg_kernel,
                        hipFuncAttributeMaxDynamicSharedMemorySize, smem_bytes);
    agg_kernel<<<NB, 512, smem_bytes, stream>>>(
        ego, rel, cntA, baseA, cntR, baseR, recsA, recsR, W1, b1, W2, b2, out);
}

// Round 6
// 1784.688 us; speedup vs baseline: 1.7187x; 1.7187x over previous
//
#include <hip/hip_runtime.h>

#define NN 100000
#define NE 3200000
#define NR 32
#define DIM 64
#define RB 128                          // rows per bucket (2^7)
#define NB ((NN + RB - 1) / RB)         // 782 buckets
#define EPB 8192                        // edges per block in bucket kernels
#define NBLK_E ((NE + EPB - 1) / EPB)   // 391

typedef unsigned int u32;
typedef unsigned long long u64;

__device__ __forceinline__ float bits_f(u32 u) {
    union { u32 u; float f; } x; x.u = u; return x.f;
}
__device__ __forceinline__ float rdlane_f(float v, int l) {
    return __int_as_float(__builtin_amdgcn_readlane(__float_as_int(v), l));
}

// ---------------------------------------------------------------------------
// ws layout (38.4 MB + 32KB):
//   int cntA[NB], cntR[NB], curA[NB], curR[NB], baseA[NB], baseR[NB] (18.8KB)
//   u64 recsA[NE] @ +32768  main edges: {hi: val f32, lo: rowlow(7b)<<17 | col(17b)}
//   u32 recsR[NE]           rel edges:  {val bf16<<16 | rowlow(7b)<<5 | rel(5b)}
// side[] is staged in d_out (agg writes it, mlp rewrites in place).
// ---------------------------------------------------------------------------

// K1a: per-bucket edge counts (LDS-aggregated)
__global__ __launch_bounds__(256) void count_kernel(
    const int* __restrict__ row, const int* __restrict__ row_r,
    int* __restrict__ cntA, int* __restrict__ cntR)
{
    __shared__ int lh[2 * NB];
    for (int i = threadIdx.x; i < 2 * NB; i += 256) lh[i] = 0;
    __syncthreads();
    int base = blockIdx.x * EPB;
    for (int i = 0; i < EPB / 256; ++i) {
        int e = base + i * 256 + threadIdx.x;
        if (e < NE) {
            atomicAdd(&lh[row[e] >> 7], 1);
            atomicAdd(&lh[NB + (row_r[e] >> 7)], 1);
        }
    }
    __syncthreads();
    for (int t = threadIdx.x; t < NB; t += 256) {
        if (lh[t])      atomicAdd(&cntA[t], lh[t]);
        if (lh[NB + t]) atomicAdd(&cntR[t], lh[NB + t]);
    }
}

// K2: exclusive scan over NB (<=1024) elements, both arrays, init cursors
__global__ __launch_bounds__(1024) void scan_kernel(
    const int* __restrict__ cntA, const int* __restrict__ cntR,
    int* __restrict__ baseA, int* __restrict__ baseR,
    int* __restrict__ curA, int* __restrict__ curR)
{
    __shared__ int s[1024];
    int t = threadIdx.x;
    int v = (t < NB) ? cntA[t] : 0;
    s[t] = v; __syncthreads();
    for (int o = 1; o < 1024; o <<= 1) {
        int x = (t >= o) ? s[t - o] : 0; __syncthreads();
        s[t] += x; __syncthreads();
    }
    if (t < NB) { baseA[t] = s[t] - v; curA[t] = s[t] - v; }
    __syncthreads();
    int v2 = (t < NB) ? cntR[t] : 0;
    s[t] = v2; __syncthreads();
    for (int o = 1; o < 1024; o <<= 1) {
        int x = (t >= o) ? s[t - o] : 0; __syncthreads();
        s[t] += x; __syncthreads();
    }
    if (t < NB) { baseR[t] = s[t] - v2; curR[t] = s[t] - v2; }
}

// K1b: scatter edges into bucket regions (block-ranked runs)
__global__ __launch_bounds__(256) void bucket_kernel(
    const int* __restrict__ row, const int* __restrict__ col,
    const float* __restrict__ vals,
    const int* __restrict__ row_r, const int* __restrict__ rel_i,
    const float* __restrict__ vals_r,
    int* __restrict__ curA, int* __restrict__ curR,
    u64* __restrict__ recsA, u32* __restrict__ recsR)
{
    __shared__ int lhA[NB], lhR[NB], lbA[NB], lbR[NB];
    for (int i = threadIdx.x; i < NB; i += 256) { lhA[i] = 0; lhR[i] = 0; }
    __syncthreads();
    int base = blockIdx.x * EPB;
    for (int i = 0; i < EPB / 256; ++i) {
        int e = base + i * 256 + threadIdx.x;
        if (e < NE) {
            atomicAdd(&lhA[row[e] >> 7], 1);
            atomicAdd(&lhR[row_r[e] >> 7], 1);
        }
    }
    __syncthreads();
    for (int t = threadIdx.x; t < NB; t += 256) {
        lbA[t] = lhA[t] ? atomicAdd(&curA[t], lhA[t]) : 0;
        lbR[t] = lhR[t] ? atomicAdd(&curR[t], lhR[t]) : 0;
    }
    __syncthreads();
    for (int i = threadIdx.x; i < NB; i += 256) { lhA[i] = 0; lhR[i] = 0; }
    __syncthreads();
    for (int i = 0; i < EPB / 256; ++i) {
        int e = base + i * 256 + threadIdx.x;
        if (e < NE) {
            int r = row[e], bk = r >> 7;
            int rank = atomicAdd(&lhA[bk], 1);
            union { float f; u32 u; } uv; uv.f = vals[e];
            u32 lo = (u32)col[e] | ((u32)(r & (RB - 1)) << 17);
            recsA[lbA[bk] + rank] = ((u64)uv.u << 32) | lo;

            int r2 = row_r[e], bk2 = r2 >> 7;
            int rank2 = atomicAdd(&lhR[bk2], 1);
            union { float f; u32 u; } uw; uw.f = vals_r[e];
            u32 vb = (uw.u + 0x8000u) & 0xFFFF0000u;   // bf16 round-to-nearest
            recsR[lbR[bk2] + rank2] = vb | ((u32)(r2 & (RB - 1)) << 5) | (u32)rel_i[e];
        }
    }
}

// K3: per-bucket LDS accumulation; writes side (incl. rel term) into d_out
__global__ __launch_bounds__(256) void agg_kernel(
    const float* __restrict__ ego, const float* __restrict__ rel_emb,
    const int* __restrict__ cntA, const int* __restrict__ baseA,
    const int* __restrict__ cntR, const int* __restrict__ baseR,
    const u64* __restrict__ recsA, const u32* __restrict__ recsR,
    float* __restrict__ side)
{
    __shared__ float tile[RB * DIM];    // 32 KB
    __shared__ float coeffL[RB * NR];   // 16 KB
    const int tid = threadIdx.x, wave = tid >> 6, lane = tid & 63;
    const int b = blockIdx.x;

    // register-resident 0.1 * rel_emb column for this lane's dim
    float sr[NR];
    #pragma unroll
    for (int r = 0; r < NR; ++r) sr[r] = 0.1f * rel_emb[r * DIM + lane];

    for (int i = tid; i < RB * DIM; i += 256) tile[i] = 0.0f;
    for (int i = tid; i < RB * NR; i += 256) coeffL[i] = 0.0f;
    __syncthreads();

    // ---- rel edges: coeffL[rowlow][rel] += val  (1 scalar atomic / edge) ----
    {
        int s0 = baseR[b], cnt = cntR[b];
        for (int chunk = wave * 64; chunk < cnt; chunk += 256) {
            u32 rec = (chunk + lane < cnt) ? recsR[s0 + chunk + lane] : 0u;
            float v = bits_f(rec & 0xFFFF0000u);
            int idx = (int)((rec >> 5) & 127u) * NR + (int)(rec & 31u);
            atomicAdd(&coeffL[idx], v);
        }
    }
    // ---- main edges: tile[rowlow][:] += val * ego[col][:], 8 in flight ----
    {
        int s0 = baseA[b], cnt = cntA[b];
        for (int chunk = wave * 64; chunk < cnt; chunk += 256) {
            u64 rec = (chunk + lane < cnt) ? recsA[s0 + chunk + lane] : 0ull;
            u32 lo = (u32)rec, hi = (u32)(rec >> 32);
            #pragma unroll
            for (int jb = 0; jb < 64; jb += 8) {
                float g[8], v[8]; int ra[8];
                #pragma unroll
                for (int u = 0; u < 8; ++u) {
                    u32 lj = (u32)__builtin_amdgcn_readlane((int)lo, jb + u);
                    u32 hj = (u32)__builtin_amdgcn_readlane((int)hi, jb + u);
                    g[u] = ego[(size_t)(lj & 0x1FFFFu) * DIM + lane];  // 8 indep loads
                    v[u] = bits_f(hj);
                    ra[u] = (int)(lj >> 17) * DIM + lane;
                }
                #pragma unroll
                for (int u = 0; u < 8; ++u)
                    atomicAdd(&tile[ra[u]], v[u] * g[u]);
            }
        }
    }
    __syncthreads();

    // ---- reconstruction + side write: side = tile + coeff @ (0.1*rel_emb) ----
    for (int nl = wave; nl < RB; nl += 4) {
        int n = b * RB + nl;
        if (n >= NN) break;                         // uniform per wave
        float sd = tile[nl * DIM + lane];
        float crow = (lane < NR) ? coeffL[nl * NR + lane] : 0.0f;
        #pragma unroll
        for (int r = 0; r < NR; ++r)
            sd += rdlane_f(crow, r) * sr[r];
        side[(size_t)n * DIM + lane] = sd;
    }
}

// K4: in-place MLP epilogue on d_out (side -> final), weights in registers,
//     broadcasts via v_readlane (zero LDS traffic), 2 nodes in flight.
__global__ __launch_bounds__(256) void mlp_kernel(
    const float* __restrict__ ego,
    const float* __restrict__ W1, const float* __restrict__ b1,
    const float* __restrict__ W2, const float* __restrict__ b2,
    float* __restrict__ io)
{
    const int tid = threadIdx.x, wave = tid >> 6, lane = tid & 63;
    float w1s[DIM], w2s[DIM];
    {
        const float4* W1v = (const float4*)(W1 + (size_t)lane * DIM);
        const float4* W2v = (const float4*)(W2 + (size_t)lane * DIM);
        #pragma unroll
        for (int i = 0; i < 16; ++i) {
            float4 a = W1v[i];
            w1s[4*i+0] = a.x; w1s[4*i+1] = a.y; w1s[4*i+2] = a.z; w1s[4*i+3] = a.w;
            float4 c = W2v[i];
            w2s[4*i+0] = c.x; w2s[4*i+1] = c.y; w2s[4*i+2] = c.z; w2s[4*i+3] = c.w;
        }
    }
    float bb1 = b1[lane], bb2 = b2[lane];
    int base = blockIdx.x * 64 + wave * 16;

    for (int t = 0; t < 16; t += 2) {
        int n0 = base + t;
        if (n0 >= NN) break;                        // uniform; NN even -> n1 ok
        int n1 = n0 + 1;
        float s0 = io[(size_t)n0 * DIM + lane], e0 = ego[(size_t)n0 * DIM + lane];
        float s1 = io[(size_t)n1 * DIM + lane], e1 = ego[(size_t)n1 * DIM + lane];
        float a0 = e0 + s0, c0 = e0 * s0;
        float a1 = e1 + s1, c1 = e1 * s1;
        float x0 = bb1, y0 = bb2, x1 = bb1, y1 = bb2;
        #pragma unroll
        for (int k = 0; k < DIM; ++k) {
            x0 += rdlane_f(a0, k) * w1s[k];
            y0 += rdlane_f(c0, k) * w2s[k];
            x1 += rdlane_f(a1, k) * w1s[k];
            y1 += rdlane_f(c1, k) * w2s[k];
        }
        x0 = x0 > 0.0f ? x0 : 0.01f * x0;  y0 = y0 > 0.0f ? y0 : 0.01f * y0;
        x1 = x1 > 0.0f ? x1 : 0.01f * x1;  y1 = y1 > 0.0f ? y1 : 0.01f * y1;
        io[(size_t)n0 * DIM + lane] = x0 + y0;
        io[(size_t)n1 * DIM + lane] = x1 + y1;
    }
}

extern "C" void kernel_launch(void* const* d_in, const int* in_sizes, int n_in,
                              void* d_out, int out_size, void* d_ws, size_t ws_size,
                              hipStream_t stream)
{
    const float* ego    = (const float*)d_in[0];
    const float* rel    = (const float*)d_in[1];
    const int*   row    = (const int*)  d_in[2];
    const int*   col    = (const int*)  d_in[3];
    const float* vals   = (const float*)d_in[4];
    const int*   row_r  = (const int*)  d_in[5];
    const int*   rel_i  = (const int*)  d_in[6];
    const float* vals_r = (const float*)d_in[7];
    const float* W1     = (const float*)d_in[8];
    const float* b1     = (const float*)d_in[9];
    const float* W2     = (const float*)d_in[10];
    const float* b2     = (const float*)d_in[11];
    float* out = (float*)d_out;

    int* cntA  = (int*)d_ws;
    int* cntR  = cntA + NB;
    int* curA  = cntR + NB;
    int* curR  = curA + NB;
    int* baseA = curR + NB;
    int* baseR = baseA + NB;
    u64* recsA = (u64*)((char*)d_ws + 32768);
    u32* recsR = (u32*)(recsA + NE);

    hipMemsetAsync(d_ws, 0, 32768, stream);       // zero counters

    count_kernel<<<NBLK_E, 256, 0, stream>>>(row, row_r, cntA, cntR);
    scan_kernel<<<1, 1024, 0, stream>>>(cntA, cntR, baseA, baseR, curA, curR);
    bucket_kernel<<<NBLK_E, 256, 0, stream>>>(row, col, vals, row_r, rel_i, vals_r,
                                              curA, curR, recsA, recsR);
    agg_kernel<<<NB, 256, 0, stream>>>(ego, rel, cntA, baseA, cntR, baseR,
                                       recsA, recsR, out);
    mlp_kernel<<<(NN + 63) / 64, 256, 0, stream>>>(ego, W1, b1, W2, b2, out);
}